// Round 2
// baseline (5781.917 us; speedup 1.0000x reference)
//
#include <hip/hip_runtime.h>

// BiLSTM-CRF loss. B=32 L=512 E=1024 H=512 T=32.
// R2: all kernels <64KB LDS; ws ~162MB with guard; bounded-spin lockstep
// recurrence with timeout flag; conversions fused into staging.

typedef __attribute__((ext_vector_type(8))) short bf16x8;
typedef __attribute__((ext_vector_type(4))) float f32x4;

#define DEV static __device__ __forceinline__

DEV unsigned short f2bf(float f){
  unsigned int u = __float_as_uint(f);
  u = (u + 0x7fffu + ((u >> 16) & 1u)) >> 16;   // RNE
  return (unsigned short)u;
}
DEV float bf2f(unsigned short h){ return __uint_as_float(((unsigned int)h) << 16); }
DEV float sigm(float x){ return 1.0f / (1.0f + __expf(-x)); }

__global__ void k_sentinel(float* out){ out[0] = -12345.0f; }

__global__ void k_convert(const float* __restrict__ src, unsigned short* __restrict__ dst, int n){
  int i = blockIdx.x * blockDim.x + threadIdx.x;
  int stride = gridDim.x * blockDim.x;
  for (; i < n; i += stride) dst[i] = f2bf(src[i]);
}

// ---- x-projection GEMM: (16384x1024)@(1024x2048)^T + bias, fp32 in, bf16 MFMA, bf16 out ----
__global__ __launch_bounds__(256) void k_xproj(
    const float* __restrict__ X,
    const float* __restrict__ Wf, const float* __restrict__ Wb,
    const float* __restrict__ bf_, const float* __restrict__ bb_,
    unsigned short* __restrict__ xpf, unsigned short* __restrict__ xpb)
{
  const int dir = blockIdx.z;
  const float* W = dir ? Wb : Wf;
  const float* bias = dir ? bb_ : bf_;
  unsigned short* out = dir ? xpb : xpf;
  const int m0 = blockIdx.x * 128;
  const int n0 = blockIdx.y * 128;
  __shared__ unsigned short As[128 * 40];   // pad: row stride 80B, 16B-aligned, <=2-way banks
  __shared__ unsigned short Bs[128 * 40];
  const int tid = threadIdx.x;
  const int lane = tid & 63, w = tid >> 6;
  const int lr = lane & 15, lq = lane >> 4;
  const int wm = (w & 1) * 64, wn = (w >> 1) * 64;

  f32x4 acc[4][4];
  #pragma unroll
  for (int i = 0; i < 4; i++)
    #pragma unroll
    for (int j = 0; j < 4; j++) acc[i][j] = (f32x4){0.f,0.f,0.f,0.f};

  for (int kk = 0; kk < 32; ++kk){
    const int k0 = kk * 32;
    __syncthreads();
    #pragma unroll
    for (int it = 0; it < 2; ++it){
      int c = tid + 256 * it;
      int r = c >> 2, cc = c & 3;
      const float4* xs = (const float4*)&X[(size_t)(m0 + r) * 1024 + k0 + cc * 8];
      float4 a0 = xs[0], a1 = xs[1];
      const float4* wsrc = (const float4*)&W[(size_t)(n0 + r) * 1024 + k0 + cc * 8];
      float4 b0 = wsrc[0], b1 = wsrc[1];
      unsigned short oa[8], ob[8];
      oa[0]=f2bf(a0.x); oa[1]=f2bf(a0.y); oa[2]=f2bf(a0.z); oa[3]=f2bf(a0.w);
      oa[4]=f2bf(a1.x); oa[5]=f2bf(a1.y); oa[6]=f2bf(a1.z); oa[7]=f2bf(a1.w);
      ob[0]=f2bf(b0.x); ob[1]=f2bf(b0.y); ob[2]=f2bf(b0.z); ob[3]=f2bf(b0.w);
      ob[4]=f2bf(b1.x); ob[5]=f2bf(b1.y); ob[6]=f2bf(b1.z); ob[7]=f2bf(b1.w);
      *(uint4*)&As[r * 40 + cc * 8] = *(const uint4*)oa;
      *(uint4*)&Bs[r * 40 + cc * 8] = *(const uint4*)ob;
    }
    __syncthreads();
    bf16x8 a[4], b[4];
    #pragma unroll
    for (int i = 0; i < 4; i++) a[i] = *(const bf16x8*)&As[(wm + i * 16 + lr) * 40 + lq * 8];
    #pragma unroll
    for (int j = 0; j < 4; j++) b[j] = *(const bf16x8*)&Bs[(wn + j * 16 + lr) * 40 + lq * 8];
    #pragma unroll
    for (int i = 0; i < 4; i++)
      #pragma unroll
      for (int j = 0; j < 4; j++)
        acc[i][j] = __builtin_amdgcn_mfma_f32_16x16x32_bf16(a[i], b[j], acc[i][j], 0, 0, 0);
  }
  #pragma unroll
  for (int i = 0; i < 4; i++){
    #pragma unroll
    for (int j = 0; j < 4; j++){
      int col = n0 + wn + j * 16 + lr;
      float bv = bias[col];
      #pragma unroll
      for (int r = 0; r < 4; r++){
        int row = m0 + wm + i * 16 + lq * 4 + r;   // C/D: row=(lane>>4)*4+reg, col=lane&15
        out[(size_t)row * 2048 + col] = f2bf(acc[i][j][r] + bv);
      }
    }
  }
}

// ---- persistent bidirectional LSTM recurrence ----
// 128 blocks: dir = bid>>6, wg = bid&63 owns h-lanes [wg*8, wg*8+8).
// LDS: Ws 33280 + gbuf 4224 = 37.5KB (<64KB). h(t-1) A-fragments read direct from global.
__global__ __launch_bounds__(256) void k_lstm(
    const unsigned short* __restrict__ xpf, const unsigned short* __restrict__ xpb,
    const float* __restrict__ whhf, const float* __restrict__ whhb,
    unsigned short* __restrict__ hbuf,
    unsigned int* __restrict__ arrive)
{
  const int bid = blockIdx.x;
  const int dir = bid >> 6;
  const int wg  = bid & 63;
  const int hi0 = wg * 8;
  const unsigned short* xp  = dir ? xpb  : xpf;
  const float* whh = dir ? whhb : whhf;
  unsigned int* arr = arrive + dir;
  unsigned int* tflag = arrive + 2;
  unsigned short* hb = hbuf + (size_t)dir * (512u * 32u * 512u);

  __shared__ unsigned short Ws[32 * 520];  // row gt*8+j -> global gate row gt*512+hi0+j
  __shared__ float gbuf[32 * 33];          // [batch][32 owned gate rows]

  const int tid = threadIdx.x;
  const int lane = tid & 63, w = tid >> 6;
  const int lr = lane & 15, lq = lane >> 4;
  const int tm = w & 1, tn = w >> 1;

  // one-time: stage w_hh slice fp32->bf16 into LDS
  #pragma unroll
  for (int it = 0; it < 8; ++it){
    int c = tid + 256 * it;
    int r = c >> 6, cc = c & 63;
    int ng = (r >> 3) * 512 + hi0 + (r & 7);
    const float4* src = (const float4*)&whh[(size_t)ng * 512 + cc * 8];
    float4 f0 = src[0], f1 = src[1];
    unsigned short o[8];
    o[0]=f2bf(f0.x); o[1]=f2bf(f0.y); o[2]=f2bf(f0.z); o[3]=f2bf(f0.w);
    o[4]=f2bf(f1.x); o[5]=f2bf(f1.y); o[6]=f2bf(f1.z); o[7]=f2bf(f1.w);
    *(uint4*)&Ws[r * 520 + cc * 8] = *(const uint4*)o;
  }
  __syncthreads();

  const int eb = tid >> 3, ej = tid & 7;   // epilogue: (batch eb, h-lane ej)
  float creg = 0.0f;

  for (int s = 0; s < 512; ++s){
    const int tt = dir ? (511 - s) : s;
    if (s > 0){
      if (tid == 0){
        unsigned int target = 64u * (unsigned int)s;
        int spins = 0;
        while (__hip_atomic_load(arr, __ATOMIC_ACQUIRE, __HIP_MEMORY_SCOPE_AGENT) < target){
          __builtin_amdgcn_s_sleep(2);
          if (++spins > (1 << 15)){   // ~1.7ms cap: hang-proof, flags starvation
            __hip_atomic_fetch_add(tflag, 1u, __ATOMIC_RELAXED, __HIP_MEMORY_SCOPE_AGENT);
            break;
          }
        }
      }
      __syncthreads();
      const unsigned short* hsrc = hb + (size_t)(s - 1) * (32 * 512);
      f32x4 acc = (f32x4){0.f,0.f,0.f,0.f};
      #pragma unroll
      for (int kk = 0; kk < 16; ++kk){
        bf16x8 a = *(const bf16x8*)&hsrc[(size_t)(tm * 16 + lr) * 512 + kk * 32 + lq * 8];
        bf16x8 b = *(const bf16x8*)&Ws[(tn * 16 + lr) * 520 + kk * 32 + lq * 8];
        acc = __builtin_amdgcn_mfma_f32_16x16x32_bf16(a, b, acc, 0, 0, 0);
      }
      #pragma unroll
      for (int r = 0; r < 4; r++)
        gbuf[(tm * 16 + lq * 4 + r) * 33 + tn * 16 + lr] = acc[r];
      __syncthreads();
    }
    {
      size_t rowbase = ((size_t)(eb * 512 + tt)) * 2048 + hi0 + ej;
      float xi = bf2f(xp[rowbase]);
      float xf = bf2f(xp[rowbase + 512]);
      float xg = bf2f(xp[rowbase + 1024]);
      float xo = bf2f(xp[rowbase + 1536]);
      float gi = 0.f, gf = 0.f, gg = 0.f, go = 0.f;
      if (s > 0){
        gi = gbuf[eb * 33 + ej];
        gf = gbuf[eb * 33 + 8 + ej];
        gg = gbuf[eb * 33 + 16 + ej];
        go = gbuf[eb * 33 + 24 + ej];
      }
      float iv = sigm(xi + gi), fv = sigm(xf + gf);
      float gv = tanhf(xg + gg), ov = sigm(xo + go);
      creg = fv * creg + iv * gv;
      float hv = ov * tanhf(creg);
      hb[((size_t)s * 32 + eb) * 512 + hi0 + ej] = f2bf(hv);
    }
    __syncthreads();   // all hb stores drained (vmcnt(0) before barrier)
    if (tid == 0){
      __threadfence();  // agent-scope: flush L2 so remote XCDs see hb
      __hip_atomic_fetch_add(arr, 1u, __ATOMIC_RELEASE, __HIP_MEMORY_SCOPE_AGENT);
    }
  }
}

// ---- LayerNorm: wave per (b,t) row; reads hbuf both dirs, writes hnorm [b*512+t][1024] ----
__global__ __launch_bounds__(256) void k_ln(
    const unsigned short* __restrict__ hbuf,
    const float* __restrict__ g, const float* __restrict__ bta,
    unsigned short* __restrict__ hnorm)
{
  int row = blockIdx.x * 4 + (threadIdx.x >> 6);
  int lane = threadIdx.x & 63;
  int b = row >> 9, t = row & 511;
  const unsigned short* fsrc = hbuf + ((size_t)t * 32 + b) * 512;
  const unsigned short* bsrc = hbuf + (size_t)(512u * 32u * 512u) + ((size_t)(511 - t) * 32 + b) * 512;
  uint4 u0 = *(const uint4*)&fsrc[lane * 8];
  uint4 u1 = *(const uint4*)&bsrc[lane * 8];
  const unsigned short* p0 = (const unsigned short*)&u0;
  const unsigned short* p1 = (const unsigned short*)&u1;
  float x[16];
  float sum = 0.f, ssq = 0.f;
  #pragma unroll
  for (int j = 0; j < 8; j++){ x[j] = bf2f(p0[j]); x[8 + j] = bf2f(p1[j]); }
  #pragma unroll
  for (int j = 0; j < 16; j++){ sum += x[j]; ssq += x[j] * x[j]; }
  #pragma unroll
  for (int off = 32; off; off >>= 1){ sum += __shfl_xor(sum, off); ssq += __shfl_xor(ssq, off); }
  float mean = sum * (1.0f / 1024.0f);
  float var = ssq * (1.0f / 1024.0f) - mean * mean;
  float rstd = rsqrtf(var + 1e-5f);
  unsigned short* dst = hnorm + (size_t)row * 1024;
  unsigned short o0[8], o1[8];
  #pragma unroll
  for (int j = 0; j < 8; j++){
    int i0 = lane * 8 + j, i1 = 512 + lane * 8 + j;
    o0[j] = f2bf((x[j]     - mean) * rstd * g[i0] + bta[i0]);
    o1[j] = f2bf((x[8 + j] - mean) * rstd * g[i1] + bta[i1]);
  }
  *(uint4*)&dst[lane * 8]       = *(const uint4*)o0;
  *(uint4*)&dst[512 + lane * 8] = *(const uint4*)o1;
}

// ---- emissions GEMM: (16384x1024)@(1024x32) + b_tag, no LDS, direct fragments ----
__global__ __launch_bounds__(256) void k_emis(
    const unsigned short* __restrict__ hnorm,
    const unsigned short* __restrict__ wtag,
    const float* __restrict__ btag,
    float* __restrict__ emis)
{
  const int m0 = blockIdx.x * 128;
  const int tid = threadIdx.x;
  const int lane = tid & 63, w = tid >> 6;
  const int lr = lane & 15, lq = lane >> 4;
  f32x4 acc[2][2];
  #pragma unroll
  for (int i = 0; i < 2; i++)
    #pragma unroll
    for (int j = 0; j < 2; j++) acc[i][j] = (f32x4){0.f,0.f,0.f,0.f};

  for (int kk = 0; kk < 32; ++kk){
    const int k0 = kk * 32;
    bf16x8 a[2], b[2];
    #pragma unroll
    for (int i = 0; i < 2; i++)
      a[i] = *(const bf16x8*)&hnorm[(size_t)(m0 + w * 32 + i * 16 + lr) * 1024 + k0 + lq * 8];
    #pragma unroll
    for (int j = 0; j < 2; j++)
      b[j] = *(const bf16x8*)&wtag[(size_t)(j * 16 + lr) * 1024 + k0 + lq * 8];
    #pragma unroll
    for (int i = 0; i < 2; i++)
      #pragma unroll
      for (int j = 0; j < 2; j++)
        acc[i][j] = __builtin_amdgcn_mfma_f32_16x16x32_bf16(a[i], b[j], acc[i][j], 0, 0, 0);
  }
  #pragma unroll
  for (int i = 0; i < 2; i++)
    #pragma unroll
    for (int j = 0; j < 2; j++){
      int col = j * 16 + lr;
      float bv = btag[col];
      #pragma unroll
      for (int r = 0; r < 4; r++){
        int row = m0 + w * 32 + i * 16 + lq * 4 + r;
        emis[(size_t)row * 32 + col] = acc[i][j][r] + bv;
      }
    }
}

// ---- CRF log-likelihood (wave per batch) ----
__global__ __launch_bounds__(64) void k_crf(
    const float* __restrict__ emis, const int* __restrict__ tags,
    const int* __restrict__ mask, const float* __restrict__ trans,
    const float* __restrict__ start_t, const float* __restrict__ end_t,
    float* __restrict__ llh)
{
  const int b = blockIdx.x;
  const int lane = threadIdx.x;
  __shared__ float tr[32 * 33];
  __shared__ float al[32];
  #pragma unroll
  for (int it = 0; it < 16; ++it){
    int c = lane + 64 * it;
    tr[(c >> 5) * 33 + (c & 31)] = trans[c];
  }
  __syncthreads();
  float part = 0.0f; int cnt = 0;
  for (int t = lane; t < 512; t += 64){
    int tg = tags[b * 512 + t];
    cnt += mask[b * 512 + t];
    if (t == 0){
      part += start_t[tg] + emis[((size_t)b * 512) * 32 + tg];
    } else {
      int tp = tags[b * 512 + t - 1];
      float mf = (float)mask[b * 512 + t];
      part += (tr[tp * 33 + tg] + emis[((size_t)b * 512 + t) * 32 + tg]) * mf;
    }
  }
  #pragma unroll
  for (int off = 32; off; off >>= 1){ part += __shfl_xor(part, off); cnt += __shfl_xor(cnt, off); }
  int col = lane & 31;
  if (lane < 32) al[lane] = start_t[lane] + emis[((size_t)b * 512) * 32 + lane];
  __syncthreads();
  for (int t = 1; t < 512; ++t){
    float e = emis[((size_t)b * 512 + t) * 32 + col];
    int mk = mask[b * 512 + t];
    float m = -1e30f;
    #pragma unroll
    for (int i = 0; i < 32; i++) m = fmaxf(m, al[i] + tr[i * 33 + col]);
    float sexp = 0.0f;
    #pragma unroll
    for (int i = 0; i < 32; i++) sexp += __expf(al[i] + tr[i * 33 + col] - m);
    float nxt = e + m + __logf(sexp);
    float na = mk ? nxt : al[col];
    __syncthreads();
    if (lane < 32) al[lane] = na;
    __syncthreads();
  }
  float v = (lane < 32) ? (al[lane] + end_t[lane]) : -1e30f;
  float mv = v;
  #pragma unroll
  for (int off = 32; off; off >>= 1) mv = fmaxf(mv, __shfl_xor(mv, off));
  float se = (lane < 32) ? __expf(v - mv) : 0.0f;
  #pragma unroll
  for (int off = 32; off; off >>= 1) se += __shfl_xor(se, off);
  if (lane == 0){
    int last_idx = cnt - 1;
    int lt = tags[b * 512 + last_idx];
    float num = part + end_t[lt];
    float logZ = mv + __logf(se);
    llh[b] = num - logZ;
  }
}

__global__ void k_final(const float* __restrict__ llh, const unsigned int* __restrict__ tflag,
                        float* __restrict__ out){
  int lane = threadIdx.x;
  float v = (lane < 32) ? llh[lane] : 0.0f;
  #pragma unroll
  for (int off = 32; off; off >>= 1) v += __shfl_xor(v, off);
  if (lane == 0) out[0] = -(v * (1.0f / 32.0f)) + (tflag[0] ? 1.0e6f : 0.0f);
}

extern "C" void kernel_launch(void* const* d_in, const int* in_sizes, int n_in,
                              void* d_out, int out_size, void* d_ws, size_t ws_size,
                              hipStream_t stream)
{
  (void)in_sizes; (void)n_in; (void)out_size;
  const float* emb   = (const float*)d_in[0];
  const int*   tags  = (const int*)d_in[1];
  const int*   amask = (const int*)d_in[2];
  const float* wihf  = (const float*)d_in[3];
  const float* whhf  = (const float*)d_in[4];
  const float* bf_   = (const float*)d_in[5];
  const float* wihb  = (const float*)d_in[6];
  const float* whhb  = (const float*)d_in[7];
  const float* bb_   = (const float*)d_in[8];
  const float* lng   = (const float*)d_in[9];
  const float* lnb   = (const float*)d_in[10];
  const float* wtag  = (const float*)d_in[11];
  const float* btag  = (const float*)d_in[12];
  const float* trans = (const float*)d_in[13];
  const float* stt   = (const float*)d_in[14];
  const float* endt  = (const float*)d_in[15];

  unsigned char* wsp = (unsigned char*)d_ws;
  size_t off = 0;
  auto alloc = [&](size_t bytes) -> void* {
    void* p = wsp + off; off += (bytes + 255) & ~(size_t)255; return p;
  };
  unsigned short* xpf   = (unsigned short*)alloc(33554432ull * 2);  // 64MB, reused as hnorm
  unsigned short* xpb   = (unsigned short*)alloc(33554432ull * 2);  // 64MB
  unsigned short* hbuf  = (unsigned short*)alloc(16777216ull * 2);  // 32MB [dir][s][b][h]
  unsigned short* wtagb = (unsigned short*)alloc(32768ull * 2);
  float* emis = (float*)alloc(524288ull * 4);
  float* llh  = (float*)alloc(64 * 4);
  unsigned int* arrive = (unsigned int*)alloc(256);
  unsigned short* hnorm = xpf;  // alias: xp dead after k_lstm

  if (off > ws_size){
    k_sentinel<<<1, 1, 0, stream>>>((float*)d_out);
    return;
  }

  hipMemsetAsync(arrive, 0, 256, stream);
  k_convert<<<32, 256, 0, stream>>>(wtag, wtagb, 32768);
  k_xproj<<<dim3(128, 16, 2), 256, 0, stream>>>(emb, wihf, wihb, bf_, bb_, xpf, xpb);
  k_lstm<<<128, 256, 0, stream>>>(xpf, xpb, whhf, whhb, hbuf, arrive);
  k_ln<<<4096, 256, 0, stream>>>(hbuf, lng, lnb, hnorm);
  k_emis<<<128, 256, 0, stream>>>(hnorm, wtagb, btag, emis);
  k_crf<<<32, 64, 0, stream>>>(emis, tags, amask, trans, stt, endt, llh);
  k_final<<<1, 64, 0, stream>>>(llh, arrive + 2, (float*)d_out);
}

// Round 3
// 4498.141 us; speedup vs baseline: 1.2854x; 1.2854x over previous
//
#include <hip/hip_runtime.h>

// BiLSTM-CRF loss. B=32 L=512 E=1024 H=512 T=32.
// R3: lockstep recurrence re-protocol — relaxed atomic-exchange publication
// (coherence-point, no wbl2), relaxed poll + single acquire, xp prefetch
// before poll. Everything else identical to R2 (passed, absmax 0).

typedef __attribute__((ext_vector_type(8))) short bf16x8;
typedef __attribute__((ext_vector_type(4))) float f32x4;

#define DEV static __device__ __forceinline__

DEV unsigned short f2bf(float f){
  unsigned int u = __float_as_uint(f);
  u = (u + 0x7fffu + ((u >> 16) & 1u)) >> 16;   // RNE
  return (unsigned short)u;
}
DEV float bf2f(unsigned short h){ return __uint_as_float(((unsigned int)h) << 16); }
DEV float sigm(float x){ return 1.0f / (1.0f + __expf(-x)); }

__global__ void k_sentinel(float* out){ out[0] = -12345.0f; }

__global__ void k_convert(const float* __restrict__ src, unsigned short* __restrict__ dst, int n){
  int i = blockIdx.x * blockDim.x + threadIdx.x;
  int stride = gridDim.x * blockDim.x;
  for (; i < n; i += stride) dst[i] = f2bf(src[i]);
}

// ---- x-projection GEMM: (16384x1024)@(1024x2048)^T + bias, fp32 in, bf16 MFMA, bf16 out ----
__global__ __launch_bounds__(256) void k_xproj(
    const float* __restrict__ X,
    const float* __restrict__ Wf, const float* __restrict__ Wb,
    const float* __restrict__ bf_, const float* __restrict__ bb_,
    unsigned short* __restrict__ xpf, unsigned short* __restrict__ xpb)
{
  const int dir = blockIdx.z;
  const float* W = dir ? Wb : Wf;
  const float* bias = dir ? bb_ : bf_;
  unsigned short* out = dir ? xpb : xpf;
  const int m0 = blockIdx.x * 128;
  const int n0 = blockIdx.y * 128;
  __shared__ unsigned short As[128 * 40];
  __shared__ unsigned short Bs[128 * 40];
  const int tid = threadIdx.x;
  const int lane = tid & 63, w = tid >> 6;
  const int lr = lane & 15, lq = lane >> 4;
  const int wm = (w & 1) * 64, wn = (w >> 1) * 64;

  f32x4 acc[4][4];
  #pragma unroll
  for (int i = 0; i < 4; i++)
    #pragma unroll
    for (int j = 0; j < 4; j++) acc[i][j] = (f32x4){0.f,0.f,0.f,0.f};

  for (int kk = 0; kk < 32; ++kk){
    const int k0 = kk * 32;
    __syncthreads();
    #pragma unroll
    for (int it = 0; it < 2; ++it){
      int c = tid + 256 * it;
      int r = c >> 2, cc = c & 3;
      const float4* xs = (const float4*)&X[(size_t)(m0 + r) * 1024 + k0 + cc * 8];
      float4 a0 = xs[0], a1 = xs[1];
      const float4* wsrc = (const float4*)&W[(size_t)(n0 + r) * 1024 + k0 + cc * 8];
      float4 b0 = wsrc[0], b1 = wsrc[1];
      unsigned short oa[8], ob[8];
      oa[0]=f2bf(a0.x); oa[1]=f2bf(a0.y); oa[2]=f2bf(a0.z); oa[3]=f2bf(a0.w);
      oa[4]=f2bf(a1.x); oa[5]=f2bf(a1.y); oa[6]=f2bf(a1.z); oa[7]=f2bf(a1.w);
      ob[0]=f2bf(b0.x); ob[1]=f2bf(b0.y); ob[2]=f2bf(b0.z); ob[3]=f2bf(b0.w);
      ob[4]=f2bf(b1.x); ob[5]=f2bf(b1.y); ob[6]=f2bf(b1.z); ob[7]=f2bf(b1.w);
      *(uint4*)&As[r * 40 + cc * 8] = *(const uint4*)oa;
      *(uint4*)&Bs[r * 40 + cc * 8] = *(const uint4*)ob;
    }
    __syncthreads();
    bf16x8 a[4], b[4];
    #pragma unroll
    for (int i = 0; i < 4; i++) a[i] = *(const bf16x8*)&As[(wm + i * 16 + lr) * 40 + lq * 8];
    #pragma unroll
    for (int j = 0; j < 4; j++) b[j] = *(const bf16x8*)&Bs[(wn + j * 16 + lr) * 40 + lq * 8];
    #pragma unroll
    for (int i = 0; i < 4; i++)
      #pragma unroll
      for (int j = 0; j < 4; j++)
        acc[i][j] = __builtin_amdgcn_mfma_f32_16x16x32_bf16(a[i], b[j], acc[i][j], 0, 0, 0);
  }
  #pragma unroll
  for (int i = 0; i < 4; i++){
    #pragma unroll
    for (int j = 0; j < 4; j++){
      int col = n0 + wn + j * 16 + lr;
      float bv = bias[col];
      #pragma unroll
      for (int r = 0; r < 4; r++){
        int row = m0 + wm + i * 16 + lq * 4 + r;
        out[(size_t)row * 2048 + col] = f2bf(acc[i][j][r] + bv);
      }
    }
  }
}

// ---- persistent bidirectional LSTM recurrence ----
// 128 blocks: dir = bid>>6, wg = bid&63 owns h-lanes [wg*8, wg*8+8).
// Publication: LDS-staged slice -> 64 u64 relaxed agent atomic exchanges
// (coherence point, no wbl2) -> vmcnt(0) -> relaxed counter add.
// Wait: relaxed poll, one acquire after, then vectorized b128 h reads.
__global__ __launch_bounds__(256) void k_lstm(
    const unsigned short* __restrict__ xpf, const unsigned short* __restrict__ xpb,
    const float* __restrict__ whhf, const float* __restrict__ whhb,
    unsigned long long* __restrict__ hpub,   // [dir][s][b][h/4] u64 units
    unsigned int* __restrict__ arrive)
{
  const int bid = blockIdx.x;
  const int dir = bid >> 6;
  const int wg  = bid & 63;
  const int hi0 = wg * 8;
  const unsigned short* xp  = dir ? xpb  : xpf;
  const float* whh = dir ? whhb : whhf;
  unsigned int* arr = arrive + dir;
  unsigned int* tflag = arrive + 2;
  unsigned long long* hp = hpub + (size_t)dir * (512u * 32u * 128u);

  __shared__ unsigned short Ws[32 * 520];  // row gt*8+j -> global gate row gt*512+hi0+j
  __shared__ float gbuf[32 * 33];          // [batch][32 owned gate rows]
  __shared__ unsigned long long hstage[64]; // [b][8] bf16 slice, u64 view

  const int tid = threadIdx.x;
  const int lane = tid & 63, w = tid >> 6;
  const int lr = lane & 15, lq = lane >> 4;
  const int tm = w & 1, tn = w >> 1;

  // one-time: stage w_hh slice fp32->bf16 into LDS
  #pragma unroll
  for (int it = 0; it < 8; ++it){
    int c = tid + 256 * it;
    int r = c >> 6, cc = c & 63;
    int ng = (r >> 3) * 512 + hi0 + (r & 7);
    const float4* src = (const float4*)&whh[(size_t)ng * 512 + cc * 8];
    float4 f0 = src[0], f1 = src[1];
    unsigned short o[8];
    o[0]=f2bf(f0.x); o[1]=f2bf(f0.y); o[2]=f2bf(f0.z); o[3]=f2bf(f0.w);
    o[4]=f2bf(f1.x); o[5]=f2bf(f1.y); o[6]=f2bf(f1.z); o[7]=f2bf(f1.w);
    *(uint4*)&Ws[r * 520 + cc * 8] = *(const uint4*)o;
  }
  __syncthreads();

  const int eb = tid >> 3, ej = tid & 7;   // epilogue: (batch eb, h-lane ej)
  float creg = 0.0f;

  for (int s = 0; s < 512; ++s){
    const int tt = dir ? (511 - s) : s;
    // prefetch x gates BEFORE the wait (independent of h(t-1))
    size_t rowbase = ((size_t)(eb * 512 + tt)) * 2048 + hi0 + ej;
    float xi = bf2f(xp[rowbase]);
    float xf = bf2f(xp[rowbase + 512]);
    float xg = bf2f(xp[rowbase + 1024]);
    float xo = bf2f(xp[rowbase + 1536]);
    float gi = 0.f, gf = 0.f, gg = 0.f, go = 0.f;

    if (s > 0){
      if (tid == 0){
        unsigned int target = 64u * (unsigned int)s;
        int spins = 0;
        while (__hip_atomic_load(arr, __ATOMIC_RELAXED, __HIP_MEMORY_SCOPE_AGENT) < target){
          __builtin_amdgcn_s_sleep(1);
          if (++spins > (1 << 15)){
            __hip_atomic_fetch_add(tflag, 1u, __ATOMIC_RELAXED, __HIP_MEMORY_SCOPE_AGENT);
            break;
          }
        }
        (void)__hip_atomic_load(arr, __ATOMIC_ACQUIRE, __HIP_MEMORY_SCOPE_AGENT); // single inv
      }
      __syncthreads();
      const unsigned short* hsrc = (const unsigned short*)(hp + (size_t)(s - 1) * (32 * 128));
      bf16x8 a[16];
      #pragma unroll
      for (int kk = 0; kk < 16; ++kk)
        a[kk] = *(const bf16x8*)&hsrc[(size_t)(tm * 16 + lr) * 512 + kk * 32 + lq * 8];
      f32x4 acc = (f32x4){0.f,0.f,0.f,0.f};
      #pragma unroll
      for (int kk = 0; kk < 16; ++kk){
        bf16x8 b = *(const bf16x8*)&Ws[(tn * 16 + lr) * 520 + kk * 32 + lq * 8];
        acc = __builtin_amdgcn_mfma_f32_16x16x32_bf16(a[kk], b, acc, 0, 0, 0);
      }
      #pragma unroll
      for (int r = 0; r < 4; r++)
        gbuf[(tm * 16 + lq * 4 + r) * 33 + tn * 16 + lr] = acc[r];
      __syncthreads();
      gi = gbuf[eb * 33 + ej];
      gf = gbuf[eb * 33 + 8 + ej];
      gg = gbuf[eb * 33 + 16 + ej];
      go = gbuf[eb * 33 + 24 + ej];
    }

    float iv = sigm(xi + gi), fv = sigm(xf + gf);
    float gv = tanhf(xg + gg), ov = sigm(xo + go);
    creg = fv * creg + iv * gv;
    float hv = ov * tanhf(creg);
    ((unsigned short*)hstage)[eb * 8 + ej] = f2bf(hv);
    __syncthreads();   // hstage complete (also fences gbuf reuse)

    if (tid < 64){
      unsigned long long v = hstage[tid];
      // u64 index: [s][b = tid>>1][h-chunk = wg*2 + (tid&1)]
      (void)__hip_atomic_exchange(
          &hp[(size_t)s * (32 * 128) + (size_t)(tid >> 1) * 128 + wg * 2 + (tid & 1)],
          v, __ATOMIC_RELAXED, __HIP_MEMORY_SCOPE_AGENT);
    }
    asm volatile("s_waitcnt vmcnt(0)" ::: "memory");  // publishes at coherence point
    if (tid == 0)
      __hip_atomic_fetch_add(arr, 1u, __ATOMIC_RELAXED, __HIP_MEMORY_SCOPE_AGENT);
  }
}

// ---- LayerNorm: wave per (b,t) row; reads hpub both dirs, writes hnorm [b*512+t][1024] ----
__global__ __launch_bounds__(256) void k_ln(
    const unsigned short* __restrict__ hbuf,
    const float* __restrict__ g, const float* __restrict__ bta,
    unsigned short* __restrict__ hnorm)
{
  int row = blockIdx.x * 4 + (threadIdx.x >> 6);
  int lane = threadIdx.x & 63;
  int b = row >> 9, t = row & 511;
  const unsigned short* fsrc = hbuf + ((size_t)t * 32 + b) * 512;
  const unsigned short* bsrc = hbuf + (size_t)(512u * 32u * 512u) + ((size_t)(511 - t) * 32 + b) * 512;
  uint4 u0 = *(const uint4*)&fsrc[lane * 8];
  uint4 u1 = *(const uint4*)&bsrc[lane * 8];
  const unsigned short* p0 = (const unsigned short*)&u0;
  const unsigned short* p1 = (const unsigned short*)&u1;
  float x[16];
  float sum = 0.f, ssq = 0.f;
  #pragma unroll
  for (int j = 0; j < 8; j++){ x[j] = bf2f(p0[j]); x[8 + j] = bf2f(p1[j]); }
  #pragma unroll
  for (int j = 0; j < 16; j++){ sum += x[j]; ssq += x[j] * x[j]; }
  #pragma unroll
  for (int off = 32; off; off >>= 1){ sum += __shfl_xor(sum, off); ssq += __shfl_xor(ssq, off); }
  float mean = sum * (1.0f / 1024.0f);
  float var = ssq * (1.0f / 1024.0f) - mean * mean;
  float rstd = rsqrtf(var + 1e-5f);
  unsigned short* dst = hnorm + (size_t)row * 1024;
  unsigned short o0[8], o1[8];
  #pragma unroll
  for (int j = 0; j < 8; j++){
    int i0 = lane * 8 + j, i1 = 512 + lane * 8 + j;
    o0[j] = f2bf((x[j]     - mean) * rstd * g[i0] + bta[i0]);
    o1[j] = f2bf((x[8 + j] - mean) * rstd * g[i1] + bta[i1]);
  }
  *(uint4*)&dst[lane * 8]       = *(const uint4*)o0;
  *(uint4*)&dst[512 + lane * 8] = *(const uint4*)o1;
}

// ---- emissions GEMM: (16384x1024)@(1024x32) + b_tag, no LDS, direct fragments ----
__global__ __launch_bounds__(256) void k_emis(
    const unsigned short* __restrict__ hnorm,
    const unsigned short* __restrict__ wtag,
    const float* __restrict__ btag,
    float* __restrict__ emis)
{
  const int m0 = blockIdx.x * 128;
  const int tid = threadIdx.x;
  const int lane = tid & 63, w = tid >> 6;
  const int lr = lane & 15, lq = lane >> 4;
  f32x4 acc[2][2];
  #pragma unroll
  for (int i = 0; i < 2; i++)
    #pragma unroll
    for (int j = 0; j < 2; j++) acc[i][j] = (f32x4){0.f,0.f,0.f,0.f};

  for (int kk = 0; kk < 32; ++kk){
    const int k0 = kk * 32;
    bf16x8 a[2], b[2];
    #pragma unroll
    for (int i = 0; i < 2; i++)
      a[i] = *(const bf16x8*)&hnorm[(size_t)(m0 + w * 32 + i * 16 + lr) * 1024 + k0 + lq * 8];
    #pragma unroll
    for (int j = 0; j < 2; j++)
      b[j] = *(const bf16x8*)&wtag[(size_t)(j * 16 + lr) * 1024 + k0 + lq * 8];
    #pragma unroll
    for (int i = 0; i < 2; i++)
      #pragma unroll
      for (int j = 0; j < 2; j++)
        acc[i][j] = __builtin_amdgcn_mfma_f32_16x16x32_bf16(a[i], b[j], acc[i][j], 0, 0, 0);
  }
  #pragma unroll
  for (int i = 0; i < 2; i++)
    #pragma unroll
    for (int j = 0; j < 2; j++){
      int col = j * 16 + lr;
      float bv = btag[col];
      #pragma unroll
      for (int r = 0; r < 4; r++){
        int row = m0 + w * 32 + i * 16 + lq * 4 + r;
        emis[(size_t)row * 32 + col] = acc[i][j][r] + bv;
      }
    }
}

// ---- CRF log-likelihood (wave per batch) ----
__global__ __launch_bounds__(64) void k_crf(
    const float* __restrict__ emis, const int* __restrict__ tags,
    const int* __restrict__ mask, const float* __restrict__ trans,
    const float* __restrict__ start_t, const float* __restrict__ end_t,
    float* __restrict__ llh)
{
  const int b = blockIdx.x;
  const int lane = threadIdx.x;
  __shared__ float tr[32 * 33];
  __shared__ float al[32];
  #pragma unroll
  for (int it = 0; it < 16; ++it){
    int c = lane + 64 * it;
    tr[(c >> 5) * 33 + (c & 31)] = trans[c];
  }
  __syncthreads();
  float part = 0.0f; int cnt = 0;
  for (int t = lane; t < 512; t += 64){
    int tg = tags[b * 512 + t];
    cnt += mask[b * 512 + t];
    if (t == 0){
      part += start_t[tg] + emis[((size_t)b * 512) * 32 + tg];
    } else {
      int tp = tags[b * 512 + t - 1];
      float mf = (float)mask[b * 512 + t];
      part += (tr[tp * 33 + tg] + emis[((size_t)b * 512 + t) * 32 + tg]) * mf;
    }
  }
  #pragma unroll
  for (int off = 32; off; off >>= 1){ part += __shfl_xor(part, off); cnt += __shfl_xor(cnt, off); }
  int col = lane & 31;
  if (lane < 32) al[lane] = start_t[lane] + emis[((size_t)b * 512) * 32 + lane];
  __syncthreads();
  for (int t = 1; t < 512; ++t){
    float e = emis[((size_t)b * 512 + t) * 32 + col];
    int mk = mask[b * 512 + t];
    float m = -1e30f;
    #pragma unroll
    for (int i = 0; i < 32; i++) m = fmaxf(m, al[i] + tr[i * 33 + col]);
    float sexp = 0.0f;
    #pragma unroll
    for (int i = 0; i < 32; i++) sexp += __expf(al[i] + tr[i * 33 + col] - m);
    float nxt = e + m + __logf(sexp);
    float na = mk ? nxt : al[col];
    __syncthreads();
    if (lane < 32) al[lane] = na;
    __syncthreads();
  }
  float v = (lane < 32) ? (al[lane] + end_t[lane]) : -1e30f;
  float mv = v;
  #pragma unroll
  for (int off = 32; off; off >>= 1) mv = fmaxf(mv, __shfl_xor(mv, off));
  float se = (lane < 32) ? __expf(v - mv) : 0.0f;
  #pragma unroll
  for (int off = 32; off; off >>= 1) se += __shfl_xor(se, off);
  if (lane == 0){
    int last_idx = cnt - 1;
    int lt = tags[b * 512 + last_idx];
    float num = part + end_t[lt];
    float logZ = mv + __logf(se);
    llh[b] = num - logZ;
  }
}

__global__ void k_final(const float* __restrict__ llh, const unsigned int* __restrict__ tflag,
                        float* __restrict__ out){
  int lane = threadIdx.x;
  float v = (lane < 32) ? llh[lane] : 0.0f;
  #pragma unroll
  for (int off = 32; off; off >>= 1) v += __shfl_xor(v, off);
  if (lane == 0) out[0] = -(v * (1.0f / 32.0f)) + (tflag[0] ? 1.0e6f : 0.0f);
}

extern "C" void kernel_launch(void* const* d_in, const int* in_sizes, int n_in,
                              void* d_out, int out_size, void* d_ws, size_t ws_size,
                              hipStream_t stream)
{
  (void)in_sizes; (void)n_in; (void)out_size;
  const float* emb   = (const float*)d_in[0];
  const int*   tags  = (const int*)d_in[1];
  const int*   amask = (const int*)d_in[2];
  const float* wihf  = (const float*)d_in[3];
  const float* whhf  = (const float*)d_in[4];
  const float* bf_   = (const float*)d_in[5];
  const float* wihb  = (const float*)d_in[6];
  const float* whhb  = (const float*)d_in[7];
  const float* bb_   = (const float*)d_in[8];
  const float* lng   = (const float*)d_in[9];
  const float* lnb   = (const float*)d_in[10];
  const float* wtag  = (const float*)d_in[11];
  const float* btag  = (const float*)d_in[12];
  const float* trans = (const float*)d_in[13];
  const float* stt   = (const float*)d_in[14];
  const float* endt  = (const float*)d_in[15];

  unsigned char* wsp = (unsigned char*)d_ws;
  size_t off = 0;
  auto alloc = [&](size_t bytes) -> void* {
    void* p = wsp + off; off += (bytes + 255) & ~(size_t)255; return p;
  };
  unsigned short* xpf   = (unsigned short*)alloc(33554432ull * 2);  // 64MB, reused as hnorm
  unsigned short* xpb   = (unsigned short*)alloc(33554432ull * 2);  // 64MB
  unsigned long long* hpub = (unsigned long long*)alloc(16777216ull * 2);  // 32MB [dir][s][b][h]
  unsigned short* wtagb = (unsigned short*)alloc(32768ull * 2);
  float* emis = (float*)alloc(524288ull * 4);
  float* llh  = (float*)alloc(64 * 4);
  unsigned int* arrive = (unsigned int*)alloc(256);
  unsigned short* hnorm = xpf;  // alias: xp dead after k_lstm

  if (off > ws_size){
    k_sentinel<<<1, 1, 0, stream>>>((float*)d_out);
    return;
  }

  hipMemsetAsync(arrive, 0, 256, stream);
  k_convert<<<32, 256, 0, stream>>>(wtag, wtagb, 32768);
  k_xproj<<<dim3(128, 16, 2), 256, 0, stream>>>(emb, wihf, wihb, bf_, bb_, xpf, xpb);
  k_lstm<<<128, 256, 0, stream>>>(xpf, xpb, whhf, whhb, hpub, arrive);
  k_ln<<<4096, 256, 0, stream>>>((const unsigned short*)hpub, lng, lnb, hnorm);
  k_emis<<<128, 256, 0, stream>>>(hnorm, wtagb, btag, emis);
  k_crf<<<32, 64, 0, stream>>>(emis, tags, amask, trans, stt, endt, llh);
  k_final<<<1, 64, 0, stream>>>(llh, arrive + 2, (float*)d_out);
}

// Round 4
// 3837.113 us; speedup vs baseline: 1.5068x; 1.1723x over previous
//
#include <hip/hip_runtime.h>

// BiLSTM-CRF loss. B=32 L=512 E=1024 H=512 T=32.
// R4: recurrence sync re-protocol — per-producer tag array (no same-address
// RMW contention) polled by one wave-wide ballot; transposed MFMA so each
// thread holds (i,f,g,o) of its own (batch,h) in regs (gbuf + 1 barrier gone).
// k_xproj/k_ln/k_emis/k_crf unchanged from R3 (passed, absmax 0).

typedef __attribute__((ext_vector_type(8))) short bf16x8;
typedef __attribute__((ext_vector_type(4))) float f32x4;

#define DEV static __device__ __forceinline__

DEV unsigned short f2bf(float f){
  unsigned int u = __float_as_uint(f);
  u = (u + 0x7fffu + ((u >> 16) & 1u)) >> 16;   // RNE
  return (unsigned short)u;
}
DEV float bf2f(unsigned short h){ return __uint_as_float(((unsigned int)h) << 16); }
DEV float sigm(float x){ return 1.0f / (1.0f + __expf(-x)); }

__global__ void k_sentinel(float* out){ out[0] = -12345.0f; }

__global__ void k_convert(const float* __restrict__ src, unsigned short* __restrict__ dst, int n){
  int i = blockIdx.x * blockDim.x + threadIdx.x;
  int stride = gridDim.x * blockDim.x;
  for (; i < n; i += stride) dst[i] = f2bf(src[i]);
}

// ---- x-projection GEMM: (16384x1024)@(1024x2048)^T + bias, fp32 in, bf16 MFMA, bf16 out ----
__global__ __launch_bounds__(256) void k_xproj(
    const float* __restrict__ X,
    const float* __restrict__ Wf, const float* __restrict__ Wb,
    const float* __restrict__ bf_, const float* __restrict__ bb_,
    unsigned short* __restrict__ xpf, unsigned short* __restrict__ xpb)
{
  const int dir = blockIdx.z;
  const float* W = dir ? Wb : Wf;
  const float* bias = dir ? bb_ : bf_;
  unsigned short* out = dir ? xpb : xpf;
  const int m0 = blockIdx.x * 128;
  const int n0 = blockIdx.y * 128;
  __shared__ unsigned short As[128 * 40];
  __shared__ unsigned short Bs[128 * 40];
  const int tid = threadIdx.x;
  const int lane = tid & 63, w = tid >> 6;
  const int lr = lane & 15, lq = lane >> 4;
  const int wm = (w & 1) * 64, wn = (w >> 1) * 64;

  f32x4 acc[4][4];
  #pragma unroll
  for (int i = 0; i < 4; i++)
    #pragma unroll
    for (int j = 0; j < 4; j++) acc[i][j] = (f32x4){0.f,0.f,0.f,0.f};

  for (int kk = 0; kk < 32; ++kk){
    const int k0 = kk * 32;
    __syncthreads();
    #pragma unroll
    for (int it = 0; it < 2; ++it){
      int c = tid + 256 * it;
      int r = c >> 2, cc = c & 3;
      const float4* xs = (const float4*)&X[(size_t)(m0 + r) * 1024 + k0 + cc * 8];
      float4 a0 = xs[0], a1 = xs[1];
      const float4* wsrc = (const float4*)&W[(size_t)(n0 + r) * 1024 + k0 + cc * 8];
      float4 b0 = wsrc[0], b1 = wsrc[1];
      unsigned short oa[8], ob[8];
      oa[0]=f2bf(a0.x); oa[1]=f2bf(a0.y); oa[2]=f2bf(a0.z); oa[3]=f2bf(a0.w);
      oa[4]=f2bf(a1.x); oa[5]=f2bf(a1.y); oa[6]=f2bf(a1.z); oa[7]=f2bf(a1.w);
      ob[0]=f2bf(b0.x); ob[1]=f2bf(b0.y); ob[2]=f2bf(b0.z); ob[3]=f2bf(b0.w);
      ob[4]=f2bf(b1.x); ob[5]=f2bf(b1.y); ob[6]=f2bf(b1.z); ob[7]=f2bf(b1.w);
      *(uint4*)&As[r * 40 + cc * 8] = *(const uint4*)oa;
      *(uint4*)&Bs[r * 40 + cc * 8] = *(const uint4*)ob;
    }
    __syncthreads();
    bf16x8 a[4], b[4];
    #pragma unroll
    for (int i = 0; i < 4; i++) a[i] = *(const bf16x8*)&As[(wm + i * 16 + lr) * 40 + lq * 8];
    #pragma unroll
    for (int j = 0; j < 4; j++) b[j] = *(const bf16x8*)&Bs[(wn + j * 16 + lr) * 40 + lq * 8];
    #pragma unroll
    for (int i = 0; i < 4; i++)
      #pragma unroll
      for (int j = 0; j < 4; j++)
        acc[i][j] = __builtin_amdgcn_mfma_f32_16x16x32_bf16(a[i], b[j], acc[i][j], 0, 0, 0);
  }
  #pragma unroll
  for (int i = 0; i < 4; i++){
    #pragma unroll
    for (int j = 0; j < 4; j++){
      int col = n0 + wn + j * 16 + lr;
      float bv = bias[col];
      #pragma unroll
      for (int r = 0; r < 4; r++){
        int row = m0 + wm + i * 16 + lq * 4 + r;
        out[(size_t)row * 2048 + col] = f2bf(acc[i][j][r] + bv);
      }
    }
  }
}

// ---- persistent bidirectional LSTM recurrence ----
// 128 blocks: dir = bid>>6, wg = bid&63 owns h-lanes [wg*8, wg*8+8).
// MFMA transposed: A = W_hh slice (M = 32 rows ordered h_local*4+gate),
// B = h(t-1) (N = 32 batches). Thread (wave tm,tn; lane lq,lr) owns
// (batch = tn*16+lr, h_local = tm*4+lq); acc = (i,f,g,o) preacts in regs.
// Publish: LDS slice -> 64 u64 relaxed xchg -> vmcnt(0) -> own-tag xchg.
// Wait: wave0 lanes poll 64 tags, ballot; single acquire; barrier.
__global__ __launch_bounds__(256) void k_lstm(
    const unsigned short* __restrict__ xpf, const unsigned short* __restrict__ xpb,
    const float* __restrict__ whhf, const float* __restrict__ whhb,
    unsigned long long* __restrict__ hpub,   // [dir][s][b][h/4] u64 units
    unsigned int* __restrict__ tags,          // [dir][64] step tags
    unsigned int* __restrict__ tflag)
{
  const int bid = blockIdx.x;
  const int dir = bid >> 6;
  const int wg  = bid & 63;
  const int hi0 = wg * 8;
  const unsigned short* xp  = dir ? xpb  : xpf;
  const float* whh = dir ? whhb : whhf;
  unsigned int* mytags = tags + dir * 64;
  unsigned long long* hp = hpub + (size_t)dir * (512u * 4096u);

  __shared__ unsigned short Ws[32 * 520];   // row r32 -> W row (r32&3)*512 + hi0 + (r32>>4)*4 + ((r32>>2)&3)
  __shared__ unsigned long long hstage[64]; // [b][8 h] bf16 slice, u64 view

  const int tid = threadIdx.x;
  const int lane = tid & 63, w = tid >> 6;
  const int lr = lane & 15, lq = lane >> 4;
  const int tm = w & 1, tn = w >> 1;
  const int myb = tn * 16 + lr;     // owned batch
  const int myh = tm * 4 + lq;      // owned h-lane within slice [0,8)

  // one-time: stage w_hh slice fp32->bf16 into LDS, rows interleaved h*4+gate
  #pragma unroll
  for (int it = 0; it < 8; ++it){
    int c = tid + 256 * it;
    int r = c >> 6, cc = c & 63;
    int ng = (r & 3) * 512 + hi0 + ((r >> 4) << 2) + ((r >> 2) & 3);
    const float4* src = (const float4*)&whh[(size_t)ng * 512 + cc * 8];
    float4 f0 = src[0], f1 = src[1];
    unsigned short o[8];
    o[0]=f2bf(f0.x); o[1]=f2bf(f0.y); o[2]=f2bf(f0.z); o[3]=f2bf(f0.w);
    o[4]=f2bf(f1.x); o[5]=f2bf(f1.y); o[6]=f2bf(f1.z); o[7]=f2bf(f1.w);
    *(uint4*)&Ws[r * 520 + cc * 8] = *(const uint4*)o;
  }
  __syncthreads();

  float creg = 0.0f;

  for (int s = 0; s < 512; ++s){
    const int tt = dir ? (511 - s) : s;
    // prefetch x gates BEFORE the wait (independent of h(t-1))
    size_t rb = ((size_t)(myb * 512 + tt)) * 2048 + hi0 + myh;
    float xi = bf2f(xp[rb]);
    float xf = bf2f(xp[rb + 512]);
    float xg = bf2f(xp[rb + 1024]);
    float xo = bf2f(xp[rb + 1536]);
    float gi = 0.f, gf = 0.f, gg = 0.f, go = 0.f;

    if (s > 0){
      if (w == 0){
        const unsigned int target = (unsigned int)s;
        int spins = 0;
        unsigned int v = __hip_atomic_load(&mytags[lane], __ATOMIC_RELAXED, __HIP_MEMORY_SCOPE_AGENT);
        while (__ballot(v < target) != 0ull){
          if (++spins > (1 << 15)){
            if (lane == 0)
              __hip_atomic_fetch_add(tflag, 1u, __ATOMIC_RELAXED, __HIP_MEMORY_SCOPE_AGENT);
            break;
          }
          __builtin_amdgcn_s_sleep(1);
          v = __hip_atomic_load(&mytags[lane], __ATOMIC_RELAXED, __HIP_MEMORY_SCOPE_AGENT);
        }
        if (lane == 0)
          (void)__hip_atomic_load(&mytags[0], __ATOMIC_ACQUIRE, __HIP_MEMORY_SCOPE_AGENT); // single inv
      }
      __syncthreads();
      const unsigned short* hsrc = (const unsigned short*)(hp + (size_t)(s - 1) * 4096);
      f32x4 acc = (f32x4){0.f,0.f,0.f,0.f};
      #pragma unroll
      for (int kk = 0; kk < 16; ++kk){
        bf16x8 a = *(const bf16x8*)&Ws[(tm * 16 + lr) * 520 + kk * 32 + lq * 8];
        bf16x8 b = *(const bf16x8*)&hsrc[(size_t)(tn * 16 + lr) * 512 + kk * 32 + lq * 8];
        acc = __builtin_amdgcn_mfma_f32_16x16x32_bf16(a, b, acc, 0, 0, 0);
      }
      gi = acc[0]; gf = acc[1]; gg = acc[2]; go = acc[3];
    }

    float iv = sigm(xi + gi), fv = sigm(xf + gf);
    float gv = tanhf(xg + gg), ov = sigm(xo + go);
    creg = fv * creg + iv * gv;
    float hv = ov * tanhf(creg);
    ((unsigned short*)hstage)[myb * 8 + myh] = f2bf(hv);
    __syncthreads();   // hstage complete

    if (w == 0){
      unsigned long long v = hstage[lane];
      // u64 index: [s][b = lane>>1][chunk = wg*2 + (lane&1)]
      (void)__hip_atomic_exchange(
          &hp[(size_t)s * 4096 + (size_t)(lane >> 1) * 128 + wg * 2 + (lane & 1)],
          v, __ATOMIC_RELAXED, __HIP_MEMORY_SCOPE_AGENT);
      asm volatile("s_waitcnt vmcnt(0)" ::: "memory");  // data at coherence point
      if (lane == 0)
        (void)__hip_atomic_exchange(&mytags[wg], (unsigned int)(s + 1),
                                    __ATOMIC_RELAXED, __HIP_MEMORY_SCOPE_AGENT);
    }
  }
}

// ---- LayerNorm: wave per (b,t) row; reads hpub both dirs, writes hnorm [b*512+t][1024] ----
__global__ __launch_bounds__(256) void k_ln(
    const unsigned short* __restrict__ hbuf,
    const float* __restrict__ g, const float* __restrict__ bta,
    unsigned short* __restrict__ hnorm)
{
  int row = blockIdx.x * 4 + (threadIdx.x >> 6);
  int lane = threadIdx.x & 63;
  int b = row >> 9, t = row & 511;
  const unsigned short* fsrc = hbuf + ((size_t)t * 32 + b) * 512;
  const unsigned short* bsrc = hbuf + (size_t)(512u * 32u * 512u) + ((size_t)(511 - t) * 32 + b) * 512;
  uint4 u0 = *(const uint4*)&fsrc[lane * 8];
  uint4 u1 = *(const uint4*)&bsrc[lane * 8];
  const unsigned short* p0 = (const unsigned short*)&u0;
  const unsigned short* p1 = (const unsigned short*)&u1;
  float x[16];
  float sum = 0.f, ssq = 0.f;
  #pragma unroll
  for (int j = 0; j < 8; j++){ x[j] = bf2f(p0[j]); x[8 + j] = bf2f(p1[j]); }
  #pragma unroll
  for (int j = 0; j < 16; j++){ sum += x[j]; ssq += x[j] * x[j]; }
  #pragma unroll
  for (int off = 32; off; off >>= 1){ sum += __shfl_xor(sum, off); ssq += __shfl_xor(ssq, off); }
  float mean = sum * (1.0f / 1024.0f);
  float var = ssq * (1.0f / 1024.0f) - mean * mean;
  float rstd = rsqrtf(var + 1e-5f);
  unsigned short* dst = hnorm + (size_t)row * 1024;
  unsigned short o0[8], o1[8];
  #pragma unroll
  for (int j = 0; j < 8; j++){
    int i0 = lane * 8 + j, i1 = 512 + lane * 8 + j;
    o0[j] = f2bf((x[j]     - mean) * rstd * g[i0] + bta[i0]);
    o1[j] = f2bf((x[8 + j] - mean) * rstd * g[i1] + bta[i1]);
  }
  *(uint4*)&dst[lane * 8]       = *(const uint4*)o0;
  *(uint4*)&dst[512 + lane * 8] = *(const uint4*)o1;
}

// ---- emissions GEMM: (16384x1024)@(1024x32) + b_tag, no LDS, direct fragments ----
__global__ __launch_bounds__(256) void k_emis(
    const unsigned short* __restrict__ hnorm,
    const unsigned short* __restrict__ wtag,
    const float* __restrict__ btag,
    float* __restrict__ emis)
{
  const int m0 = blockIdx.x * 128;
  const int tid = threadIdx.x;
  const int lane = tid & 63, w = tid >> 6;
  const int lr = lane & 15, lq = lane >> 4;
  f32x4 acc[2][2];
  #pragma unroll
  for (int i = 0; i < 2; i++)
    #pragma unroll
    for (int j = 0; j < 2; j++) acc[i][j] = (f32x4){0.f,0.f,0.f,0.f};

  for (int kk = 0; kk < 32; ++kk){
    const int k0 = kk * 32;
    bf16x8 a[2], b[2];
    #pragma unroll
    for (int i = 0; i < 2; i++)
      a[i] = *(const bf16x8*)&hnorm[(size_t)(m0 + w * 32 + i * 16 + lr) * 1024 + k0 + lq * 8];
    #pragma unroll
    for (int j = 0; j < 2; j++)
      b[j] = *(const bf16x8*)&wtag[(size_t)(j * 16 + lr) * 1024 + k0 + lq * 8];
    #pragma unroll
    for (int i = 0; i < 2; i++)
      #pragma unroll
      for (int j = 0; j < 2; j++)
        acc[i][j] = __builtin_amdgcn_mfma_f32_16x16x32_bf16(a[i], b[j], acc[i][j], 0, 0, 0);
  }
  #pragma unroll
  for (int i = 0; i < 2; i++)
    #pragma unroll
    for (int j = 0; j < 2; j++){
      int col = j * 16 + lr;
      float bv = btag[col];
      #pragma unroll
      for (int r = 0; r < 4; r++){
        int row = m0 + w * 32 + i * 16 + lq * 4 + r;
        emis[(size_t)row * 32 + col] = acc[i][j][r] + bv;
      }
    }
}

// ---- CRF log-likelihood (wave per batch) ----
__global__ __launch_bounds__(64) void k_crf(
    const float* __restrict__ emis, const int* __restrict__ tags,
    const int* __restrict__ mask, const float* __restrict__ trans,
    const float* __restrict__ start_t, const float* __restrict__ end_t,
    float* __restrict__ llh)
{
  const int b = blockIdx.x;
  const int lane = threadIdx.x;
  __shared__ float tr[32 * 33];
  __shared__ float al[32];
  #pragma unroll
  for (int it = 0; it < 16; ++it){
    int c = lane + 64 * it;
    tr[(c >> 5) * 33 + (c & 31)] = trans[c];
  }
  __syncthreads();
  float part = 0.0f; int cnt = 0;
  for (int t = lane; t < 512; t += 64){
    int tg = tags[b * 512 + t];
    cnt += mask[b * 512 + t];
    if (t == 0){
      part += start_t[tg] + emis[((size_t)b * 512) * 32 + tg];
    } else {
      int tp = tags[b * 512 + t - 1];
      float mf = (float)mask[b * 512 + t];
      part += (tr[tp * 33 + tg] + emis[((size_t)b * 512 + t) * 32 + tg]) * mf;
    }
  }
  #pragma unroll
  for (int off = 32; off; off >>= 1){ part += __shfl_xor(part, off); cnt += __shfl_xor(cnt, off); }
  int col = lane & 31;
  if (lane < 32) al[lane] = start_t[lane] + emis[((size_t)b * 512) * 32 + lane];
  __syncthreads();
  for (int t = 1; t < 512; ++t){
    float e = emis[((size_t)b * 512 + t) * 32 + col];
    int mk = mask[b * 512 + t];
    float m = -1e30f;
    #pragma unroll
    for (int i = 0; i < 32; i++) m = fmaxf(m, al[i] + tr[i * 33 + col]);
    float sexp = 0.0f;
    #pragma unroll
    for (int i = 0; i < 32; i++) sexp += __expf(al[i] + tr[i * 33 + col] - m);
    float nxt = e + m + __logf(sexp);
    float na = mk ? nxt : al[col];
    __syncthreads();
    if (lane < 32) al[lane] = na;
    __syncthreads();
  }
  float v = (lane < 32) ? (al[lane] + end_t[lane]) : -1e30f;
  float mv = v;
  #pragma unroll
  for (int off = 32; off; off >>= 1) mv = fmaxf(mv, __shfl_xor(mv, off));
  float se = (lane < 32) ? __expf(v - mv) : 0.0f;
  #pragma unroll
  for (int off = 32; off; off >>= 1) se += __shfl_xor(se, off);
  if (lane == 0){
    int last_idx = cnt - 1;
    int lt = tags[b * 512 + last_idx];
    float num = part + end_t[lt];
    float logZ = mv + __logf(se);
    llh[b] = num - logZ;
  }
}

__global__ void k_final(const float* __restrict__ llh, const unsigned int* __restrict__ tflag,
                        float* __restrict__ out){
  int lane = threadIdx.x;
  float v = (lane < 32) ? llh[lane] : 0.0f;
  #pragma unroll
  for (int off = 32; off; off >>= 1) v += __shfl_xor(v, off);
  if (lane == 0) out[0] = -(v * (1.0f / 32.0f)) + (tflag[0] ? 1.0e6f : 0.0f);
}

extern "C" void kernel_launch(void* const* d_in, const int* in_sizes, int n_in,
                              void* d_out, int out_size, void* d_ws, size_t ws_size,
                              hipStream_t stream)
{
  (void)in_sizes; (void)n_in; (void)out_size;
  const float* emb   = (const float*)d_in[0];
  const int*   tags  = (const int*)d_in[1];
  const int*   amask = (const int*)d_in[2];
  const float* wihf  = (const float*)d_in[3];
  const float* whhf  = (const float*)d_in[4];
  const float* bf_   = (const float*)d_in[5];
  const float* wihb  = (const float*)d_in[6];
  const float* whhb  = (const float*)d_in[7];
  const float* bb_   = (const float*)d_in[8];
  const float* lng   = (const float*)d_in[9];
  const float* lnb   = (const float*)d_in[10];
  const float* wtag  = (const float*)d_in[11];
  const float* btag  = (const float*)d_in[12];
  const float* trans = (const float*)d_in[13];
  const float* stt   = (const float*)d_in[14];
  const float* endt  = (const float*)d_in[15];

  unsigned char* wsp = (unsigned char*)d_ws;
  size_t off = 0;
  auto alloc = [&](size_t bytes) -> void* {
    void* p = wsp + off; off += (bytes + 255) & ~(size_t)255; return p;
  };
  unsigned short* xpf   = (unsigned short*)alloc(33554432ull * 2);  // 64MB, reused as hnorm
  unsigned short* xpb   = (unsigned short*)alloc(33554432ull * 2);  // 64MB
  unsigned long long* hpub = (unsigned long long*)alloc(16777216ull * 2);  // 32MB [dir][s][b][h]
  unsigned short* wtagb = (unsigned short*)alloc(32768ull * 2);
  float* emis = (float*)alloc(524288ull * 4);
  float* llh  = (float*)alloc(64 * 4);
  unsigned int* sync = (unsigned int*)alloc(1024);  // [0..127] tags, [128] tflag
  unsigned short* hnorm = xpf;  // alias: xp dead after k_lstm

  if (off > ws_size){
    k_sentinel<<<1, 1, 0, stream>>>((float*)d_out);
    return;
  }

  hipMemsetAsync(sync, 0, 1024, stream);
  k_convert<<<32, 256, 0, stream>>>(wtag, wtagb, 32768);
  k_xproj<<<dim3(128, 16, 2), 256, 0, stream>>>(emb, wihf, wihb, bf_, bb_, xpf, xpb);
  k_lstm<<<128, 256, 0, stream>>>(xpf, xpb, whhf, whhb, hpub, sync, sync + 128);
  k_ln<<<4096, 256, 0, stream>>>((const unsigned short*)hpub, lng, lnb, hnorm);
  k_emis<<<128, 256, 0, stream>>>(hnorm, wtagb, btag, emis);
  k_crf<<<32, 64, 0, stream>>>(emis, tags, amask, trans, stt, endt, llh);
  k_final<<<1, 64, 0, stream>>>(llh, sync + 128, (float*)d_out);
}